// Round 15
// baseline (122.764 us; speedup 1.0000x reference)
//
#include <hip/hip_runtime.h>
#include <math.h>

// ---------------- complex helpers ----------------
__device__ __forceinline__ float2 cmul(float2 a, float2 b) {
    return make_float2(a.x * b.x - a.y * b.y, a.x * b.y + a.y * b.x);
}
__device__ __forceinline__ float2 cadd(float2 a, float2 b) {
    return make_float2(a.x + b.x, a.y + b.y);
}

// ================= compile-time: numpy-legacy MT19937 (RandomState(42)) op generation ========
// Algorithm verified bit-exact Rounds 1-14 (absmax 0.0). Gate sequence baked at compile time.
struct CxOps { int ty[57]; int wa[57]; int wb[57]; };

constexpr CxOps cx_gen() {
    CxOps S{};
    unsigned mt[624] = {};
    mt[0] = 42u;
    for (int i = 1; i < 624; ++i)
        mt[i] = 1812433253u * (mt[i - 1] ^ (mt[i - 1] >> 30)) + (unsigned)i;
    int mti = 624;
    auto nextu = [&]() constexpr -> unsigned {
        if (mti >= 624) {
            for (int i = 0; i < 624; ++i) {
                unsigned y = (mt[i] & 0x80000000u) | (mt[(i + 1) % 624] & 0x7fffffffu);
                mt[i] = mt[(i + 397) % 624] ^ (y >> 1) ^ ((y & 1u) ? 2567483615u : 0u);
            }
            mti = 0;
        }
        unsigned y = mt[mti++];
        y ^= y >> 11;
        y ^= (y << 7)  & 2636928640u;
        y ^= (y << 15) & 4022730752u;
        y ^= y >> 18;
        return y;
    };
    for (int k = 0; k < 50; ++k) {
        unsigned g = nextu() & 3u;
        if (g < 3u) {
            unsigned w = nextu() & 3u;
            S.ty[k] = (int)g; S.wa[k] = (int)w; S.wb[k] = 0;
        } else {
            int arr[4] = {0, 1, 2, 3};
            unsigned j3 = nextu() & 3u;
            { int tmp = arr[3]; arr[3] = arr[j3]; arr[j3] = tmp; }
            unsigned j2 = nextu() & 3u;
            while (j2 > 2u) j2 = nextu() & 3u;
            { int tmp = arr[2]; arr[2] = arr[j2]; arr[j2] = tmp; }
            unsigned j1 = nextu() & 1u;
            { int tmp = arr[1]; arr[1] = arr[j1]; arr[j1] = tmp; }
            S.ty[k] = 3; S.wa[k] = arr[0]; S.wb[k] = arr[1];
        }
    }
    S.ty[50] = 0; S.wa[50] = 0; S.wb[50] = 0;   // rx  @0  (qp[0])
    S.ty[51] = 1; S.wa[51] = 1; S.wb[51] = 0;   // ry  @1  (qp[1])
    S.ty[52] = 2; S.wa[52] = 3; S.wb[52] = 0;   // rz  @3  (qp[2])
    S.ty[53] = 3; S.wa[53] = 0; S.wb[53] = 2;   // crx @(0,2) (qp[3])
    S.ty[54] = 4; S.wa[54] = 3; S.wb[54] = 0;   // H   @3
    S.ty[55] = 5; S.wa[55] = 2; S.wb[55] = 0;   // SX  @2
    S.ty[56] = 6; S.wa[56] = 3; S.wb[56] = 0;   // CNOT@(3,0)
    return S;
}
constexpr CxOps C_OPS = cx_gen();

struct CxMeta { int cm[57]; int tm[57]; };
constexpr CxMeta cx_meta_gen() {
    CxMeta M{};
    for (int k = 0; k < 57; ++k) {
        int ty = C_OPS.ty[k];
        if (ty == 3 || ty == 6) { M.cm[k] = 8 >> C_OPS.wa[k]; M.tm[k] = 8 >> C_OPS.wb[k]; }
        else                    { M.cm[k] = 0;               M.tm[k] = 8 >> C_OPS.wa[k]; }
    }
    return M;
}
constexpr CxMeta C_META = cx_meta_gen();

// shared device body: LDS ping-pong unitary compose (Round-8 verified, I-cache-resident loop)
__device__ __forceinline__ void unitary_body(const float* __restrict__ rl,
                                             const float* __restrict__ qp,
                                             float2* __restrict__ Uout,
                                             float2 (&mats)[57][4], float2 (&buf)[2][256])
{
    const int t = threadIdx.x;
    const int r = t >> 4, c = t & 15;

    if (t < 57) {
        const int ty = C_OPS.ty[t];
        const float th = (t < 50) ? rl[t] : ((t < 54) ? qp[t - 50] : 0.f);
        float sh, ch;
        sincosf(0.5f * th, &sh, &ch);
        float2 m00, m01, m10, m11;
        if (ty == 0 || ty == 3) {
            m00 = make_float2(ch, 0.f); m01 = make_float2(0.f, -sh);
            m10 = make_float2(0.f, -sh); m11 = make_float2(ch, 0.f);
        } else if (ty == 1) {
            m00 = make_float2(ch, 0.f); m01 = make_float2(-sh, 0.f);
            m10 = make_float2(sh, 0.f); m11 = make_float2(ch, 0.f);
        } else if (ty == 2) {
            m00 = make_float2(ch, -sh); m01 = make_float2(0.f, 0.f);
            m10 = make_float2(0.f, 0.f); m11 = make_float2(ch, sh);
        } else if (ty == 4) {
            const float r_ = 0.70710678118654752f;
            m00 = make_float2(r_, 0.f); m01 = make_float2(r_, 0.f);
            m10 = make_float2(r_, 0.f); m11 = make_float2(-r_, 0.f);
        } else if (ty == 5) {
            m00 = make_float2(0.5f, 0.5f);  m01 = make_float2(0.5f, -0.5f);
            m10 = make_float2(0.5f, -0.5f); m11 = make_float2(0.5f, 0.5f);
        } else {
            m00 = make_float2(0.f, 0.f); m01 = make_float2(1.f, 0.f);
            m10 = make_float2(1.f, 0.f); m11 = make_float2(0.f, 0.f);
        }
        mats[t][0] = m00; mats[t][1] = m01; mats[t][2] = m10; mats[t][3] = m11;
    }
    buf[0][t] = make_float2((r == c) ? 1.f : 0.f, 0.f);
    __syncthreads();

    int p = 0;
    #pragma unroll 1
    for (int k = 0; k < 57; ++k) {
        const int cm = C_META.cm[k], tm = C_META.tm[k];
        const float2 m00 = mats[k][0], m01 = mats[k][1];
        const float2 m10 = mats[k][2], m11 = mats[k][3];
        const float2 me = buf[p][t];
        const float2 pv = buf[p][(r ^ tm) * 16 + c];
        float2 nv;
        if (r & tm) nv = cadd(cmul(m10, pv), cmul(m11, me));
        else        nv = cadd(cmul(m00, me), cmul(m01, pv));
        if ((r & cm) != cm) nv = me;
        buf[p ^ 1][t] = nv;
        __syncthreads();
        p ^= 1;
    }
    Uout[t] = buf[p][t];
}

__global__ __launch_bounds__(256)
void unitary_lds_kernel(const float* __restrict__ rl, const float* __restrict__ qp,
                        float2* __restrict__ Uout)
{
    __shared__ float2 mats[57][4];
    __shared__ float2 buf[2][256];
    unitary_body(rl, qp, Uout, mats, buf);
}

// ================= Kernel 1: conv1 + relu + maxpool2 (half-split) + unitary tail-block ======
__global__ __launch_bounds__(256, 4)
void conv1_kernel(const float* __restrict__ X, const float* __restrict__ W1,
                  const float* __restrict__ B1, float* __restrict__ h1g,
                  const float* __restrict__ rl, const float* __restrict__ qp,
                  float2* __restrict__ Uout)
{
    const int bx = blockIdx.x, t = threadIdx.x;
    __shared__ float xin[34 * 66];

    if (bx == 2048) {
        __shared__ float2 mats[57][4];
        __shared__ float2 buf[2][256];
        unitary_body(rl, qp, Uout, mats, buf);
        return;
    }

    const int b = bx >> 1, h = bx & 1;
    const float* xb = X + (size_t)b * 4096;
    const int rbase = 32 * h - 1;
    for (int idx = t; idx < 34 * 66; idx += 256) {
        int ly = idx / 66, lx = idx - ly * 66;
        int gy = rbase + ly, gx = lx - 1;
        float v = 0.f;
        if (gy >= 0 && gy < 64 && gx >= 0 && gx < 64) v = xb[gy * 64 + gx];
        xin[idx] = v;
    }
    __syncthreads();

    #pragma unroll
    for (int j = 0; j < 2; ++j) {
        const int cell = t + 256 * j;
        const int py = cell >> 5, px = cell & 31;
        const int base = (2 * py) * 66 + 2 * px;
        float win[4][4];
        #pragma unroll
        for (int r = 0; r < 4; ++r) {
            float2 p0 = *(const float2*)&xin[base + r * 66];
            float2 p1 = *(const float2*)&xin[base + r * 66 + 2];
            win[r][0] = p0.x; win[r][1] = p0.y; win[r][2] = p1.x; win[r][3] = p1.y;
        }
        const int gcell = (16 * h + py) * 32 + px;
        #pragma unroll
        for (int g = 0; g < 2; ++g) {
            float acc[4][4];
            #pragma unroll
            for (int o = 0; o < 4; ++o) {
                float bb = B1[g * 4 + o];
                acc[o][0] = bb; acc[o][1] = bb; acc[o][2] = bb; acc[o][3] = bb;
            }
            #pragma unroll
            for (int o = 0; o < 4; ++o) {
                const float* wp = W1 + (g * 4 + o) * 9;
                #pragma unroll
                for (int ky = 0; ky < 3; ++ky)
                    #pragma unroll
                    for (int kx = 0; kx < 3; ++kx) {
                        float w = wp[ky * 3 + kx];
                        acc[o][0] = fmaf(win[ky][kx],         w, acc[o][0]);
                        acc[o][1] = fmaf(win[ky][kx + 1],     w, acc[o][1]);
                        acc[o][2] = fmaf(win[ky + 1][kx],     w, acc[o][2]);
                        acc[o][3] = fmaf(win[ky + 1][kx + 1], w, acc[o][3]);
                    }
            }
            #pragma unroll
            for (int o = 0; o < 4; ++o) {
                float m = fmaxf(fmaxf(acc[o][0], acc[o][1]), fmaxf(acc[o][2], acc[o][3]));
                h1g[((size_t)b * 8 + g * 4 + o) * 1024 + gcell] = fmaxf(m, 0.f);
            }
        }
    }
}

// ================= Kernel 2: conv2 + relu + maxpool2 + avg + quantum head (ic-chunked) ======
// Round 15: Round-14 base (ic-chunked, 21 KB LDS) with the per-chunk ic loop FULLY UNROLLED.
// Theory: with `unroll 1`, each ic iteration serially issues its 144 wave-uniform weight
// s_loads and waits lgkmcnt before its FMA block (~200 cyc scalar-fetch stall per iter that
// occupancy can't hide — R11-R14 all left dur at ~42 us). Full unroll lets the compiler
// hoist/pipeline a whole chunk's 576 weight loads ahead of the FMA stream. Chunk loop stays
// `unroll 1` so code = one chunk (~20 KB, I-cache resident per Round-7 lesson).
__global__ __launch_bounds__(256, 4)
void conv2_head_kernel(const float* __restrict__ h1g, const float* __restrict__ W2,
                       const float* __restrict__ B2, const float2* __restrict__ Ug,
                       const float* __restrict__ head_w, const float* __restrict__ head_b,
                       const float* __restrict__ bn_g, const float* __restrict__ bn_b,
                       const float* __restrict__ bn_m, const float* __restrict__ bn_v,
                       float* __restrict__ out)
{
    const int b = blockIdx.x, t = threadIdx.x;
    __shared__ float h1s[4 * 34 * 34];   // halo-padded, 4 input channels per chunk (18.5 KB)
    __shared__ float2 Ul[256];
    __shared__ float red[16 * 4];
    __shared__ float pool16[16];

    Ul[t] = Ug[t];
    for (int i = t; i < 4 * 34 * 34; i += 256) h1s[i] = 0.f;   // halo stays 0 across chunks

    const int py = t >> 4, px = t & 15;
    const int y0 = 2 * py, x0 = 2 * px;
    const int lane = t & 63, wid = t >> 6;

    float acc[16][4];
    #pragma unroll
    for (int o = 0; o < 16; ++o) {
        float bb = B2[o];
        acc[o][0] = bb; acc[o][1] = bb; acc[o][2] = bb; acc[o][3] = bb;
    }

    const float4* src = (const float4*)(h1g + (size_t)b * 8192);

    #pragma unroll 1
    for (int ch = 0; ch < 2; ++ch) {
        __syncthreads();   // chunk-0: after halo zero; chunk-1: prior reads complete
        #pragma unroll
        for (int k = 0; k < 4; ++k) {
            const int i4 = t + k * 256;          // 1024 float4s per chunk
            const float4 v = src[ch * 1024 + i4];
            const int icl = i4 >> 8, c4 = i4 & 255;
            const int y = c4 >> 3, xq = (c4 & 7) << 2;
            const int base = icl * 1156 + (y + 1) * 34 + (xq + 1);
            h1s[base + 0] = v.x; h1s[base + 1] = v.y;
            h1s[base + 2] = v.z; h1s[base + 3] = v.w;
        }
        __syncthreads();

        #pragma unroll
        for (int icl = 0; icl < 4; ++icl) {
            const int base = icl * 1156 + y0 * 34 + x0;
            float win[4][4];
            #pragma unroll
            for (int r = 0; r < 4; ++r) {
                float2 p0 = *(const float2*)&h1s[base + r * 34];
                float2 p1 = *(const float2*)&h1s[base + r * 34 + 2];
                win[r][0] = p0.x; win[r][1] = p0.y; win[r][2] = p1.x; win[r][3] = p1.y;
            }
            const float* wpi = W2 + (size_t)(ch * 4 + icl) * 9;
            #pragma unroll
            for (int o = 0; o < 16; ++o) {
                const float* wp = wpi + (size_t)o * 72;
                #pragma unroll
                for (int ky = 0; ky < 3; ++ky)
                    #pragma unroll
                    for (int kx = 0; kx < 3; ++kx) {
                        float w = wp[ky * 3 + kx];
                        acc[o][0] = fmaf(win[ky][kx],         w, acc[o][0]);
                        acc[o][1] = fmaf(win[ky][kx + 1],     w, acc[o][1]);
                        acc[o][2] = fmaf(win[ky + 1][kx],     w, acc[o][2]);
                        acc[o][3] = fmaf(win[ky + 1][kx + 1], w, acc[o][3]);
                    }
            }
        }
    }

    #pragma unroll
    for (int o = 0; o < 16; ++o) {
        float m = fmaxf(fmaxf(acc[o][0], acc[o][1]), fmaxf(acc[o][2], acc[o][3]));
        float v = fmaxf(m, 0.f);
        #pragma unroll
        for (int off = 32; off > 0; off >>= 1)
            v += __shfl_down(v, off, 64);
        if (lane == 0) red[o * 4 + wid] = v;
    }
    __syncthreads();
    if (t < 16)
        pool16[t] = (red[t * 4] + red[t * 4 + 1] + red[t * 4 + 2] + red[t * 4 + 3]) * (1.0f / 256.0f);
    __syncthreads();

    // ---- quantum head: product state from encoder, amplitude row t, <Z>, linear+BN ----
    if (t < 16) {
        float2 v0[4], v1[4];
        #pragma unroll
        for (int w = 0; w < 4; ++w) {
            float a  = pool16[w];
            float bz = pool16[4 + w];
            float gx = pool16[8 + w];
            float dl = pool16[12 + w];
            float sa, ca, sb, cb, sg, cg, sd, cd;
            sincosf(0.5f * a,  &sa, &ca);
            sincosf(0.5f * bz, &sb, &cb);
            sincosf(0.5f * gx, &sg, &cg);
            sincosf(0.5f * dl, &sd, &cd);
            float2 u0 = make_float2(ca * cb, -ca * sb);
            float2 u1 = make_float2(sa * cb,  sa * sb);
            float2 w0 = make_float2(cg * u0.x + sg * u1.y, cg * u0.y - sg * u1.x);
            float2 w1 = make_float2(sg * u0.y + cg * u1.x, -sg * u0.x + cg * u1.y);
            v0[w] = make_float2(cd * w0.x - sd * w1.x, cd * w0.y - sd * w1.y);
            v1[w] = make_float2(sd * w0.x + cd * w1.x, sd * w0.y + cd * w1.y);
        }
        float2 s01[4], s23[4];
        s01[0] = cmul(v0[0], v0[1]); s01[1] = cmul(v0[0], v1[1]);
        s01[2] = cmul(v1[0], v0[1]); s01[3] = cmul(v1[0], v1[1]);
        s23[0] = cmul(v0[2], v0[3]); s23[1] = cmul(v0[2], v1[3]);
        s23[2] = cmul(v1[2], v0[3]); s23[3] = cmul(v1[2], v1[3]);
        float2 acc2 = make_float2(0.f, 0.f);
        #pragma unroll
        for (int i = 0; i < 4; ++i)
            #pragma unroll
            for (int j = 0; j < 4; ++j) {
                float2 sij = cmul(s01[i], s23[j]);
                acc2 = cadd(acc2, cmul(Ul[t * 16 + i * 4 + j], sij));
            }
        float pr = acc2.x * acc2.x + acc2.y * acc2.y;
        float fz0 = 0.f, fz1 = 0.f, fz2 = 0.f, fz3 = 0.f;
        #pragma unroll
        for (int i = 0; i < 16; ++i) {
            float p = __shfl(pr, i, 64);
            fz0 += ((i >> 3) & 1) ? -p : p;
            fz1 += ((i >> 2) & 1) ? -p : p;
            fz2 += ((i >> 1) & 1) ? -p : p;
            fz3 += (i & 1) ? -p : p;
        }
        if (t == 0) {
            float o = head_b[0];
            o = fmaf(fz0, head_w[0], o);
            o = fmaf(fz1, head_w[1], o);
            o = fmaf(fz2, head_w[2], o);
            o = fmaf(fz3, head_w[3], o);
            o = bn_g[0] * (o - bn_m[0]) / sqrtf(bn_v[0] + 1e-5f) + bn_b[0];
            out[b] = o;
        }
    }
}

// ================= Fallback path (Round-1/2 verified, used only if ws too small) =================
__global__ __launch_bounds__(256, 2)
void fused_cnn_kernel(const float* __restrict__ X,
                      const float* __restrict__ W1, const float* __restrict__ B1,
                      const float* __restrict__ W2, const float* __restrict__ B2,
                      float* __restrict__ pooled)
{
    const int b = blockIdx.x;
    const int t = threadIdx.x;
    __shared__ float xin[66 * 66];
    __shared__ float h1[8 * 34 * 34];
    __shared__ float red[16 * 4];

    const float* xb = X + (size_t)b * (64 * 64);
    for (int idx = t; idx < 66 * 66; idx += 256) {
        int y = idx / 66, x = idx - y * 66;
        float v = 0.f;
        if (y >= 1 && y <= 64 && x >= 1 && x <= 64)
            v = xb[(y - 1) * 64 + (x - 1)];
        xin[idx] = v;
    }
    for (int idx = t; idx < 8 * 34 * 34; idx += 256) h1[idx] = 0.f;
    __syncthreads();

    for (int cell = t; cell < 1024; cell += 256) {
        int py = cell >> 5, px = cell & 31;
        int y0 = 2 * py, x0 = 2 * px;
        float win[4][4];
        #pragma unroll
        for (int r = 0; r < 4; ++r)
            #pragma unroll
            for (int c = 0; c < 4; ++c)
                win[r][c] = xin[(y0 + r) * 66 + (x0 + c)];
        #pragma unroll
        for (int oc = 0; oc < 8; ++oc) {
            float bb = B1[oc];
            float a00 = bb, a01 = bb, a10 = bb, a11 = bb;
            #pragma unroll
            for (int ky = 0; ky < 3; ++ky)
                #pragma unroll
                for (int kx = 0; kx < 3; ++kx) {
                    float w = W1[oc * 9 + ky * 3 + kx];
                    a00 = fmaf(win[ky][kx],         w, a00);
                    a01 = fmaf(win[ky][kx + 1],     w, a01);
                    a10 = fmaf(win[ky + 1][kx],     w, a10);
                    a11 = fmaf(win[ky + 1][kx + 1], w, a11);
                }
            float m = fmaxf(fmaxf(a00, a01), fmaxf(a10, a11));
            h1[oc * (34 * 34) + (py + 1) * 34 + (px + 1)] = fmaxf(m, 0.f);
        }
    }
    __syncthreads();

    const int py = t >> 4, px = t & 15;
    const int y0 = 2 * py, x0 = 2 * px;
    const int lane = t & 63, wid = t >> 6;

    for (int g = 0; g < 4; ++g) {
        float acc[4][4];
        #pragma unroll
        for (int o = 0; o < 4; ++o) {
            float bb = B2[g * 4 + o];
            acc[o][0] = bb; acc[o][1] = bb; acc[o][2] = bb; acc[o][3] = bb;
        }
        for (int ic = 0; ic < 8; ++ic) {
            float win[4][4];
            #pragma unroll
            for (int r = 0; r < 4; ++r)
                #pragma unroll
                for (int c = 0; c < 4; ++c)
                    win[r][c] = h1[ic * (34 * 34) + (y0 + r) * 34 + (x0 + c)];
            #pragma unroll
            for (int o = 0; o < 4; ++o) {
                const float* wp = W2 + (size_t)(g * 4 + o) * 72 + ic * 9;
                #pragma unroll
                for (int ky = 0; ky < 3; ++ky)
                    #pragma unroll
                    for (int kx = 0; kx < 3; ++kx) {
                        float w = wp[ky * 3 + kx];
                        acc[o][0] = fmaf(win[ky][kx],         w, acc[o][0]);
                        acc[o][1] = fmaf(win[ky][kx + 1],     w, acc[o][1]);
                        acc[o][2] = fmaf(win[ky + 1][kx],     w, acc[o][2]);
                        acc[o][3] = fmaf(win[ky + 1][kx + 1], w, acc[o][3]);
                    }
            }
        }
        #pragma unroll
        for (int o = 0; o < 4; ++o) {
            float m = fmaxf(fmaxf(acc[o][0], acc[o][1]), fmaxf(acc[o][2], acc[o][3]));
            float v = fmaxf(m, 0.f);
            #pragma unroll
            for (int off = 32; off > 0; off >>= 1)
                v += __shfl_down(v, off, 64);
            if (lane == 0) red[(g * 4 + o) * 4 + wid] = v;
        }
    }
    __syncthreads();
    if (t < 16) {
        float s = red[t * 4] + red[t * 4 + 1] + red[t * 4 + 2] + red[t * 4 + 3];
        pooled[(size_t)b * 16 + t] = s * (1.0f / 256.0f);
    }
}

__global__ __launch_bounds__(256)
void quantum_head_kernel(const float* __restrict__ pooled, const float2* __restrict__ Uin,
                         const float* __restrict__ head_w, const float* __restrict__ head_b,
                         const float* __restrict__ bn_g, const float* __restrict__ bn_b,
                         const float* __restrict__ bn_m, const float* __restrict__ bn_v,
                         float* __restrict__ out)
{
    __shared__ float2 U[256];
    const int t = threadIdx.x;
    U[t] = Uin[t];
    __syncthreads();
    const int b = blockIdx.x * 256 + t;

    float2 v0[4], v1[4];
    #pragma unroll
    for (int w = 0; w < 4; ++w) {
        float a  = pooled[(size_t)b * 16 + w];
        float bz = pooled[(size_t)b * 16 + 4 + w];
        float gx = pooled[(size_t)b * 16 + 8 + w];
        float dl = pooled[(size_t)b * 16 + 12 + w];
        float sa, ca, sb, cb, sg, cg, sd, cd;
        sincosf(0.5f * a,  &sa, &ca);
        sincosf(0.5f * bz, &sb, &cb);
        sincosf(0.5f * gx, &sg, &cg);
        sincosf(0.5f * dl, &sd, &cd);
        float2 u0 = make_float2(ca * cb, -ca * sb);
        float2 u1 = make_float2(sa * cb,  sa * sb);
        float2 w0 = make_float2(cg * u0.x + sg * u1.y, cg * u0.y - sg * u1.x);
        float2 w1 = make_float2(sg * u0.y + cg * u1.x, -sg * u0.x + cg * u1.y);
        v0[w] = make_float2(cd * w0.x - sd * w1.x, cd * w0.y - sd * w1.y);
        v1[w] = make_float2(sd * w0.x + cd * w1.x, sd * w0.y + cd * w1.y);
    }
    float2 s01[4], s23[4], s[16];
    s01[0] = cmul(v0[0], v0[1]); s01[1] = cmul(v0[0], v1[1]);
    s01[2] = cmul(v1[0], v0[1]); s01[3] = cmul(v1[0], v1[1]);
    s23[0] = cmul(v0[2], v0[3]); s23[1] = cmul(v0[2], v1[3]);
    s23[2] = cmul(v1[2], v0[3]); s23[3] = cmul(v1[2], v1[3]);
    #pragma unroll
    for (int i = 0; i < 4; ++i)
        #pragma unroll
        for (int j = 0; j < 4; ++j)
            s[i * 4 + j] = cmul(s01[i], s23[j]);

    float fz0 = 0.f, fz1 = 0.f, fz2 = 0.f, fz3 = 0.f;
    #pragma unroll
    for (int i = 0; i < 16; ++i) {
        float2 acc = make_float2(0.f, 0.f);
        #pragma unroll
        for (int j = 0; j < 16; ++j)
            acc = cadd(acc, cmul(U[i * 16 + j], s[j]));
        float pr = acc.x * acc.x + acc.y * acc.y;
        fz0 += ((i >> 3) & 1) ? -pr : pr;
        fz1 += ((i >> 2) & 1) ? -pr : pr;
        fz2 += ((i >> 1) & 1) ? -pr : pr;
        fz3 += (i & 1) ? -pr : pr;
    }
    float o = head_b[0];
    o = fmaf(fz0, head_w[0], o);
    o = fmaf(fz1, head_w[1], o);
    o = fmaf(fz2, head_w[2], o);
    o = fmaf(fz3, head_w[3], o);
    o = bn_g[0] * (o - bn_m[0]) / sqrtf(bn_v[0] + 1e-5f) + bn_b[0];
    out[b] = o;
}

extern "C" void kernel_launch(void* const* d_in, const int* in_sizes, int n_in,
                              void* d_out, int out_size, void* d_ws, size_t ws_size,
                              hipStream_t stream)
{
    const float* X  = (const float*)d_in[0];
    const float* W1 = (const float*)d_in[1];
    const float* B1 = (const float*)d_in[2];
    const float* W2 = (const float*)d_in[3];
    const float* B2 = (const float*)d_in[4];
    const float* RL = (const float*)d_in[5];
    const float* QP = (const float*)d_in[6];
    const float* HW = (const float*)d_in[7];
    const float* HB = (const float*)d_in[8];
    const float* BG = (const float*)d_in[9];
    const float* BB = (const float*)d_in[10];
    const float* BM = (const float*)d_in[11];
    const float* BV = (const float*)d_in[12];
    float* out = (float*)d_out;

    const size_t H1_BYTES = (size_t)1024 * 8 * 1024 * 4;   // 33.55 MB conv1-pooled maps

    if (ws_size >= H1_BYTES + 4096) {
        float*  h1g = (float*)d_ws;
        float2* U   = (float2*)((char*)d_ws + H1_BYTES);
        conv1_kernel<<<2049, 256, 0, stream>>>(X, W1, B1, h1g, RL, QP, U);
        conv2_head_kernel<<<1024, 256, 0, stream>>>(h1g, W2, B2, U,
                                                    HW, HB, BG, BB, BM, BV, out);
    } else {
        // fallback: Round-1/2 verified fused path (needs only ~66 KB of ws)
        float*  pooled = (float*)d_ws;
        float2* U      = (float2*)((char*)d_ws + 1024 * 16 * 4);
        unitary_lds_kernel<<<1, 256, 0, stream>>>(RL, QP, U);
        fused_cnn_kernel<<<1024, 256, 0, stream>>>(X, W1, B1, W2, B2, pooled);
        quantum_head_kernel<<<4, 256, 0, stream>>>(pooled, U, HW, HB, BG, BB, BM, BV, out);
    }
}

// Round 16
// 74.742 us; speedup vs baseline: 1.6425x; 1.6425x over previous
//
#include <hip/hip_runtime.h>
#include <math.h>

// ---------------- complex helpers ----------------
__device__ __forceinline__ float2 cmul(float2 a, float2 b) {
    return make_float2(a.x * b.x - a.y * b.y, a.x * b.y + a.y * b.x);
}
__device__ __forceinline__ float2 cadd(float2 a, float2 b) {
    return make_float2(a.x + b.x, a.y + b.y);
}

// ================= compile-time: numpy-legacy MT19937 (RandomState(42)) op generation ========
// Algorithm verified bit-exact Rounds 1-15 (absmax 0.0). Gate sequence baked at compile time.
struct CxOps { int ty[57]; int wa[57]; int wb[57]; };

constexpr CxOps cx_gen() {
    CxOps S{};
    unsigned mt[624] = {};
    mt[0] = 42u;
    for (int i = 1; i < 624; ++i)
        mt[i] = 1812433253u * (mt[i - 1] ^ (mt[i - 1] >> 30)) + (unsigned)i;
    int mti = 624;
    auto nextu = [&]() constexpr -> unsigned {
        if (mti >= 624) {
            for (int i = 0; i < 624; ++i) {
                unsigned y = (mt[i] & 0x80000000u) | (mt[(i + 1) % 624] & 0x7fffffffu);
                mt[i] = mt[(i + 397) % 624] ^ (y >> 1) ^ ((y & 1u) ? 2567483615u : 0u);
            }
            mti = 0;
        }
        unsigned y = mt[mti++];
        y ^= y >> 11;
        y ^= (y << 7)  & 2636928640u;
        y ^= (y << 15) & 4022730752u;
        y ^= y >> 18;
        return y;
    };
    for (int k = 0; k < 50; ++k) {
        unsigned g = nextu() & 3u;
        if (g < 3u) {
            unsigned w = nextu() & 3u;
            S.ty[k] = (int)g; S.wa[k] = (int)w; S.wb[k] = 0;
        } else {
            int arr[4] = {0, 1, 2, 3};
            unsigned j3 = nextu() & 3u;
            { int tmp = arr[3]; arr[3] = arr[j3]; arr[j3] = tmp; }
            unsigned j2 = nextu() & 3u;
            while (j2 > 2u) j2 = nextu() & 3u;
            { int tmp = arr[2]; arr[2] = arr[j2]; arr[j2] = tmp; }
            unsigned j1 = nextu() & 1u;
            { int tmp = arr[1]; arr[1] = arr[j1]; arr[j1] = tmp; }
            S.ty[k] = 3; S.wa[k] = arr[0]; S.wb[k] = arr[1];
        }
    }
    S.ty[50] = 0; S.wa[50] = 0; S.wb[50] = 0;   // rx  @0  (qp[0])
    S.ty[51] = 1; S.wa[51] = 1; S.wb[51] = 0;   // ry  @1  (qp[1])
    S.ty[52] = 2; S.wa[52] = 3; S.wb[52] = 0;   // rz  @3  (qp[2])
    S.ty[53] = 3; S.wa[53] = 0; S.wb[53] = 2;   // crx @(0,2) (qp[3])
    S.ty[54] = 4; S.wa[54] = 3; S.wb[54] = 0;   // H   @3
    S.ty[55] = 5; S.wa[55] = 2; S.wb[55] = 0;   // SX  @2
    S.ty[56] = 6; S.wa[56] = 3; S.wb[56] = 0;   // CNOT@(3,0)
    return S;
}
constexpr CxOps C_OPS = cx_gen();

struct CxMeta { int cm[57]; int tm[57]; };
constexpr CxMeta cx_meta_gen() {
    CxMeta M{};
    for (int k = 0; k < 57; ++k) {
        int ty = C_OPS.ty[k];
        if (ty == 3 || ty == 6) { M.cm[k] = 8 >> C_OPS.wa[k]; M.tm[k] = 8 >> C_OPS.wb[k]; }
        else                    { M.cm[k] = 0;               M.tm[k] = 8 >> C_OPS.wa[k]; }
    }
    return M;
}
constexpr CxMeta C_META = cx_meta_gen();

// shared device body: LDS ping-pong unitary compose (Round-8 verified, I-cache-resident loop)
__device__ __forceinline__ void unitary_body(const float* __restrict__ rl,
                                             const float* __restrict__ qp,
                                             float2* __restrict__ Uout,
                                             float2 (&mats)[57][4], float2 (&buf)[2][256])
{
    const int t = threadIdx.x;
    const int r = t >> 4, c = t & 15;

    if (t < 57) {
        const int ty = C_OPS.ty[t];
        const float th = (t < 50) ? rl[t] : ((t < 54) ? qp[t - 50] : 0.f);
        float sh, ch;
        sincosf(0.5f * th, &sh, &ch);
        float2 m00, m01, m10, m11;
        if (ty == 0 || ty == 3) {
            m00 = make_float2(ch, 0.f); m01 = make_float2(0.f, -sh);
            m10 = make_float2(0.f, -sh); m11 = make_float2(ch, 0.f);
        } else if (ty == 1) {
            m00 = make_float2(ch, 0.f); m01 = make_float2(-sh, 0.f);
            m10 = make_float2(sh, 0.f); m11 = make_float2(ch, 0.f);
        } else if (ty == 2) {
            m00 = make_float2(ch, -sh); m01 = make_float2(0.f, 0.f);
            m10 = make_float2(0.f, 0.f); m11 = make_float2(ch, sh);
        } else if (ty == 4) {
            const float r_ = 0.70710678118654752f;
            m00 = make_float2(r_, 0.f); m01 = make_float2(r_, 0.f);
            m10 = make_float2(r_, 0.f); m11 = make_float2(-r_, 0.f);
        } else if (ty == 5) {
            m00 = make_float2(0.5f, 0.5f);  m01 = make_float2(0.5f, -0.5f);
            m10 = make_float2(0.5f, -0.5f); m11 = make_float2(0.5f, 0.5f);
        } else {
            m00 = make_float2(0.f, 0.f); m01 = make_float2(1.f, 0.f);
            m10 = make_float2(1.f, 0.f); m11 = make_float2(0.f, 0.f);
        }
        mats[t][0] = m00; mats[t][1] = m01; mats[t][2] = m10; mats[t][3] = m11;
    }
    buf[0][t] = make_float2((r == c) ? 1.f : 0.f, 0.f);
    __syncthreads();

    int p = 0;
    #pragma unroll 1
    for (int k = 0; k < 57; ++k) {
        const int cm = C_META.cm[k], tm = C_META.tm[k];
        const float2 m00 = mats[k][0], m01 = mats[k][1];
        const float2 m10 = mats[k][2], m11 = mats[k][3];
        const float2 me = buf[p][t];
        const float2 pv = buf[p][(r ^ tm) * 16 + c];
        float2 nv;
        if (r & tm) nv = cadd(cmul(m10, pv), cmul(m11, me));
        else        nv = cadd(cmul(m00, me), cmul(m01, pv));
        if ((r & cm) != cm) nv = me;
        buf[p ^ 1][t] = nv;
        __syncthreads();
        p ^= 1;
    }
    Uout[t] = buf[p][t];
}

__global__ __launch_bounds__(256)
void unitary_lds_kernel(const float* __restrict__ rl, const float* __restrict__ qp,
                        float2* __restrict__ Uout)
{
    __shared__ float2 mats[57][4];
    __shared__ float2 buf[2][256];
    unitary_body(rl, qp, Uout, mats, buf);
}

// ================= Kernel 1: conv1 + relu + maxpool2 (half-split) + unitary tail-block ======
__global__ __launch_bounds__(256, 4)
void conv1_kernel(const float* __restrict__ X, const float* __restrict__ W1,
                  const float* __restrict__ B1, float* __restrict__ h1g,
                  const float* __restrict__ rl, const float* __restrict__ qp,
                  float2* __restrict__ Uout)
{
    const int bx = blockIdx.x, t = threadIdx.x;
    __shared__ float xin[34 * 66];

    if (bx == 2048) {
        __shared__ float2 mats[57][4];
        __shared__ float2 buf[2][256];
        unitary_body(rl, qp, Uout, mats, buf);
        return;
    }

    const int b = bx >> 1, h = bx & 1;
    const float* xb = X + (size_t)b * 4096;
    const int rbase = 32 * h - 1;
    for (int idx = t; idx < 34 * 66; idx += 256) {
        int ly = idx / 66, lx = idx - ly * 66;
        int gy = rbase + ly, gx = lx - 1;
        float v = 0.f;
        if (gy >= 0 && gy < 64 && gx >= 0 && gx < 64) v = xb[gy * 64 + gx];
        xin[idx] = v;
    }
    __syncthreads();

    #pragma unroll
    for (int j = 0; j < 2; ++j) {
        const int cell = t + 256 * j;
        const int py = cell >> 5, px = cell & 31;
        const int base = (2 * py) * 66 + 2 * px;
        float win[4][4];
        #pragma unroll
        for (int r = 0; r < 4; ++r) {
            float2 p0 = *(const float2*)&xin[base + r * 66];
            float2 p1 = *(const float2*)&xin[base + r * 66 + 2];
            win[r][0] = p0.x; win[r][1] = p0.y; win[r][2] = p1.x; win[r][3] = p1.y;
        }
        const int gcell = (16 * h + py) * 32 + px;
        #pragma unroll
        for (int g = 0; g < 2; ++g) {
            float acc[4][4];
            #pragma unroll
            for (int o = 0; o < 4; ++o) {
                float bb = B1[g * 4 + o];
                acc[o][0] = bb; acc[o][1] = bb; acc[o][2] = bb; acc[o][3] = bb;
            }
            #pragma unroll
            for (int o = 0; o < 4; ++o) {
                const float* wp = W1 + (g * 4 + o) * 9;
                #pragma unroll
                for (int ky = 0; ky < 3; ++ky)
                    #pragma unroll
                    for (int kx = 0; kx < 3; ++kx) {
                        float w = wp[ky * 3 + kx];
                        acc[o][0] = fmaf(win[ky][kx],         w, acc[o][0]);
                        acc[o][1] = fmaf(win[ky][kx + 1],     w, acc[o][1]);
                        acc[o][2] = fmaf(win[ky + 1][kx],     w, acc[o][2]);
                        acc[o][3] = fmaf(win[ky + 1][kx + 1], w, acc[o][3]);
                    }
            }
            #pragma unroll
            for (int o = 0; o < 4; ++o) {
                float m = fmaxf(fmaxf(acc[o][0], acc[o][1]), fmaxf(acc[o][2], acc[o][3]));
                h1g[((size_t)b * 8 + g * 4 + o) * 1024 + gcell] = fmaxf(m, 0.f);
            }
        }
    }
}

// ================= Kernel 2: conv2 + relu + maxpool2 + avg + quantum head (ic-chunked) ======
// Round 16: Round-14 base with `#pragma unroll 2` on the icl loop (the bracket midpoint):
// unroll 1 = waitcnt-serialized (45% VALU, 41 us); full unroll = spill (VGPR blowup,
// WRITE 24.6 MB, 90 us). Unroll-2 doubles latency-overlap distance at +~16 VGPR.
__global__ __launch_bounds__(256, 4)
void conv2_head_kernel(const float* __restrict__ h1g, const float* __restrict__ W2,
                       const float* __restrict__ B2, const float2* __restrict__ Ug,
                       const float* __restrict__ head_w, const float* __restrict__ head_b,
                       const float* __restrict__ bn_g, const float* __restrict__ bn_b,
                       const float* __restrict__ bn_m, const float* __restrict__ bn_v,
                       float* __restrict__ out)
{
    const int b = blockIdx.x, t = threadIdx.x;
    __shared__ float h1s[4 * 34 * 34];   // halo-padded, 4 input channels per chunk (18.5 KB)
    __shared__ float2 Ul[256];
    __shared__ float red[16 * 4];
    __shared__ float pool16[16];

    Ul[t] = Ug[t];
    for (int i = t; i < 4 * 34 * 34; i += 256) h1s[i] = 0.f;   // halo stays 0 across chunks

    const int py = t >> 4, px = t & 15;
    const int y0 = 2 * py, x0 = 2 * px;
    const int lane = t & 63, wid = t >> 6;

    float acc[16][4];
    #pragma unroll
    for (int o = 0; o < 16; ++o) {
        float bb = B2[o];
        acc[o][0] = bb; acc[o][1] = bb; acc[o][2] = bb; acc[o][3] = bb;
    }

    const float4* src = (const float4*)(h1g + (size_t)b * 8192);

    #pragma unroll 1
    for (int ch = 0; ch < 2; ++ch) {
        __syncthreads();   // chunk-0: after halo zero; chunk-1: prior reads complete
        #pragma unroll
        for (int k = 0; k < 4; ++k) {
            const int i4 = t + k * 256;          // 1024 float4s per chunk
            const float4 v = src[ch * 1024 + i4];
            const int icl = i4 >> 8, c4 = i4 & 255;
            const int y = c4 >> 3, xq = (c4 & 7) << 2;
            const int base = icl * 1156 + (y + 1) * 34 + (xq + 1);
            h1s[base + 0] = v.x; h1s[base + 1] = v.y;
            h1s[base + 2] = v.z; h1s[base + 3] = v.w;
        }
        __syncthreads();

        #pragma unroll 2
        for (int icl = 0; icl < 4; ++icl) {
            const int base = icl * 1156 + y0 * 34 + x0;
            float win[4][4];
            #pragma unroll
            for (int r = 0; r < 4; ++r) {
                float2 p0 = *(const float2*)&h1s[base + r * 34];
                float2 p1 = *(const float2*)&h1s[base + r * 34 + 2];
                win[r][0] = p0.x; win[r][1] = p0.y; win[r][2] = p1.x; win[r][3] = p1.y;
            }
            const float* wpi = W2 + (size_t)(ch * 4 + icl) * 9;
            #pragma unroll
            for (int o = 0; o < 16; ++o) {
                const float* wp = wpi + (size_t)o * 72;
                #pragma unroll
                for (int ky = 0; ky < 3; ++ky)
                    #pragma unroll
                    for (int kx = 0; kx < 3; ++kx) {
                        float w = wp[ky * 3 + kx];
                        acc[o][0] = fmaf(win[ky][kx],         w, acc[o][0]);
                        acc[o][1] = fmaf(win[ky][kx + 1],     w, acc[o][1]);
                        acc[o][2] = fmaf(win[ky + 1][kx],     w, acc[o][2]);
                        acc[o][3] = fmaf(win[ky + 1][kx + 1], w, acc[o][3]);
                    }
            }
        }
    }

    #pragma unroll
    for (int o = 0; o < 16; ++o) {
        float m = fmaxf(fmaxf(acc[o][0], acc[o][1]), fmaxf(acc[o][2], acc[o][3]));
        float v = fmaxf(m, 0.f);
        #pragma unroll
        for (int off = 32; off > 0; off >>= 1)
            v += __shfl_down(v, off, 64);
        if (lane == 0) red[o * 4 + wid] = v;
    }
    __syncthreads();
    if (t < 16)
        pool16[t] = (red[t * 4] + red[t * 4 + 1] + red[t * 4 + 2] + red[t * 4 + 3]) * (1.0f / 256.0f);
    __syncthreads();

    // ---- quantum head: product state from encoder, amplitude row t, <Z>, linear+BN ----
    if (t < 16) {
        float2 v0[4], v1[4];
        #pragma unroll
        for (int w = 0; w < 4; ++w) {
            float a  = pool16[w];
            float bz = pool16[4 + w];
            float gx = pool16[8 + w];
            float dl = pool16[12 + w];
            float sa, ca, sb, cb, sg, cg, sd, cd;
            sincosf(0.5f * a,  &sa, &ca);
            sincosf(0.5f * bz, &sb, &cb);
            sincosf(0.5f * gx, &sg, &cg);
            sincosf(0.5f * dl, &sd, &cd);
            float2 u0 = make_float2(ca * cb, -ca * sb);
            float2 u1 = make_float2(sa * cb,  sa * sb);
            float2 w0 = make_float2(cg * u0.x + sg * u1.y, cg * u0.y - sg * u1.x);
            float2 w1 = make_float2(sg * u0.y + cg * u1.x, -sg * u0.x + cg * u1.y);
            v0[w] = make_float2(cd * w0.x - sd * w1.x, cd * w0.y - sd * w1.y);
            v1[w] = make_float2(sd * w0.x + cd * w1.x, sd * w0.y + cd * w1.y);
        }
        float2 s01[4], s23[4];
        s01[0] = cmul(v0[0], v0[1]); s01[1] = cmul(v0[0], v1[1]);
        s01[2] = cmul(v1[0], v0[1]); s01[3] = cmul(v1[0], v1[1]);
        s23[0] = cmul(v0[2], v0[3]); s23[1] = cmul(v0[2], v1[3]);
        s23[2] = cmul(v1[2], v0[3]); s23[3] = cmul(v1[2], v1[3]);
        float2 acc2 = make_float2(0.f, 0.f);
        #pragma unroll
        for (int i = 0; i < 4; ++i)
            #pragma unroll
            for (int j = 0; j < 4; ++j) {
                float2 sij = cmul(s01[i], s23[j]);
                acc2 = cadd(acc2, cmul(Ul[t * 16 + i * 4 + j], sij));
            }
        float pr = acc2.x * acc2.x + acc2.y * acc2.y;
        float fz0 = 0.f, fz1 = 0.f, fz2 = 0.f, fz3 = 0.f;
        #pragma unroll
        for (int i = 0; i < 16; ++i) {
            float p = __shfl(pr, i, 64);
            fz0 += ((i >> 3) & 1) ? -p : p;
            fz1 += ((i >> 2) & 1) ? -p : p;
            fz2 += ((i >> 1) & 1) ? -p : p;
            fz3 += (i & 1) ? -p : p;
        }
        if (t == 0) {
            float o = head_b[0];
            o = fmaf(fz0, head_w[0], o);
            o = fmaf(fz1, head_w[1], o);
            o = fmaf(fz2, head_w[2], o);
            o = fmaf(fz3, head_w[3], o);
            o = bn_g[0] * (o - bn_m[0]) / sqrtf(bn_v[0] + 1e-5f) + bn_b[0];
            out[b] = o;
        }
    }
}

// ================= Fallback path (Round-1/2 verified, used only if ws too small) =================
__global__ __launch_bounds__(256, 2)
void fused_cnn_kernel(const float* __restrict__ X,
                      const float* __restrict__ W1, const float* __restrict__ B1,
                      const float* __restrict__ W2, const float* __restrict__ B2,
                      float* __restrict__ pooled)
{
    const int b = blockIdx.x;
    const int t = threadIdx.x;
    __shared__ float xin[66 * 66];
    __shared__ float h1[8 * 34 * 34];
    __shared__ float red[16 * 4];

    const float* xb = X + (size_t)b * (64 * 64);
    for (int idx = t; idx < 66 * 66; idx += 256) {
        int y = idx / 66, x = idx - y * 66;
        float v = 0.f;
        if (y >= 1 && y <= 64 && x >= 1 && x <= 64)
            v = xb[(y - 1) * 64 + (x - 1)];
        xin[idx] = v;
    }
    for (int idx = t; idx < 8 * 34 * 34; idx += 256) h1[idx] = 0.f;
    __syncthreads();

    for (int cell = t; cell < 1024; cell += 256) {
        int py = cell >> 5, px = cell & 31;
        int y0 = 2 * py, x0 = 2 * px;
        float win[4][4];
        #pragma unroll
        for (int r = 0; r < 4; ++r)
            #pragma unroll
            for (int c = 0; c < 4; ++c)
                win[r][c] = xin[(y0 + r) * 66 + (x0 + c)];
        #pragma unroll
        for (int oc = 0; oc < 8; ++oc) {
            float bb = B1[oc];
            float a00 = bb, a01 = bb, a10 = bb, a11 = bb;
            #pragma unroll
            for (int ky = 0; ky < 3; ++ky)
                #pragma unroll
                for (int kx = 0; kx < 3; ++kx) {
                    float w = W1[oc * 9 + ky * 3 + kx];
                    a00 = fmaf(win[ky][kx],         w, a00);
                    a01 = fmaf(win[ky][kx + 1],     w, a01);
                    a10 = fmaf(win[ky + 1][kx],     w, a10);
                    a11 = fmaf(win[ky + 1][kx + 1], w, a11);
                }
            float m = fmaxf(fmaxf(a00, a01), fmaxf(a10, a11));
            h1[oc * (34 * 34) + (py + 1) * 34 + (px + 1)] = fmaxf(m, 0.f);
        }
    }
    __syncthreads();

    const int py = t >> 4, px = t & 15;
    const int y0 = 2 * py, x0 = 2 * px;
    const int lane = t & 63, wid = t >> 6;

    for (int g = 0; g < 4; ++g) {
        float acc[4][4];
        #pragma unroll
        for (int o = 0; o < 4; ++o) {
            float bb = B2[g * 4 + o];
            acc[o][0] = bb; acc[o][1] = bb; acc[o][2] = bb; acc[o][3] = bb;
        }
        for (int ic = 0; ic < 8; ++ic) {
            float win[4][4];
            #pragma unroll
            for (int r = 0; r < 4; ++r)
                #pragma unroll
                for (int c = 0; c < 4; ++c)
                    win[r][c] = h1[ic * (34 * 34) + (y0 + r) * 34 + (x0 + c)];
            #pragma unroll
            for (int o = 0; o < 4; ++o) {
                const float* wp = W2 + (size_t)(g * 4 + o) * 72 + ic * 9;
                #pragma unroll
                for (int ky = 0; ky < 3; ++ky)
                    #pragma unroll
                    for (int kx = 0; kx < 3; ++kx) {
                        float w = wp[ky * 3 + kx];
                        acc[o][0] = fmaf(win[ky][kx],         w, acc[o][0]);
                        acc[o][1] = fmaf(win[ky][kx + 1],     w, acc[o][1]);
                        acc[o][2] = fmaf(win[ky + 1][kx],     w, acc[o][2]);
                        acc[o][3] = fmaf(win[ky + 1][kx + 1], w, acc[o][3]);
                    }
            }
        }
        #pragma unroll
        for (int o = 0; o < 4; ++o) {
            float m = fmaxf(fmaxf(acc[o][0], acc[o][1]), fmaxf(acc[o][2], acc[o][3]));
            float v = fmaxf(m, 0.f);
            #pragma unroll
            for (int off = 32; off > 0; off >>= 1)
                v += __shfl_down(v, off, 64);
            if (lane == 0) red[(g * 4 + o) * 4 + wid] = v;
        }
    }
    __syncthreads();
    if (t < 16) {
        float s = red[t * 4] + red[t * 4 + 1] + red[t * 4 + 2] + red[t * 4 + 3];
        pooled[(size_t)b * 16 + t] = s * (1.0f / 256.0f);
    }
}

__global__ __launch_bounds__(256)
void quantum_head_kernel(const float* __restrict__ pooled, const float2* __restrict__ Uin,
                         const float* __restrict__ head_w, const float* __restrict__ head_b,
                         const float* __restrict__ bn_g, const float* __restrict__ bn_b,
                         const float* __restrict__ bn_m, const float* __restrict__ bn_v,
                         float* __restrict__ out)
{
    __shared__ float2 U[256];
    const int t = threadIdx.x;
    U[t] = Uin[t];
    __syncthreads();
    const int b = blockIdx.x * 256 + t;

    float2 v0[4], v1[4];
    #pragma unroll
    for (int w = 0; w < 4; ++w) {
        float a  = pooled[(size_t)b * 16 + w];
        float bz = pooled[(size_t)b * 16 + 4 + w];
        float gx = pooled[(size_t)b * 16 + 8 + w];
        float dl = pooled[(size_t)b * 16 + 12 + w];
        float sa, ca, sb, cb, sg, cg, sd, cd;
        sincosf(0.5f * a,  &sa, &ca);
        sincosf(0.5f * bz, &sb, &cb);
        sincosf(0.5f * gx, &sg, &cg);
        sincosf(0.5f * dl, &sd, &cd);
        float2 u0 = make_float2(ca * cb, -ca * sb);
        float2 u1 = make_float2(sa * cb,  sa * sb);
        float2 w0 = make_float2(cg * u0.x + sg * u1.y, cg * u0.y - sg * u1.x);
        float2 w1 = make_float2(sg * u0.y + cg * u1.x, -sg * u0.x + cg * u1.y);
        v0[w] = make_float2(cd * w0.x - sd * w1.x, cd * w0.y - sd * w1.y);
        v1[w] = make_float2(sd * w0.x + cd * w1.x, sd * w0.y + cd * w1.y);
    }
    float2 s01[4], s23[4], s[16];
    s01[0] = cmul(v0[0], v0[1]); s01[1] = cmul(v0[0], v1[1]);
    s01[2] = cmul(v1[0], v0[1]); s01[3] = cmul(v1[0], v1[1]);
    s23[0] = cmul(v0[2], v0[3]); s23[1] = cmul(v0[2], v1[3]);
    s23[2] = cmul(v1[2], v0[3]); s23[3] = cmul(v1[2], v1[3]);
    #pragma unroll
    for (int i = 0; i < 4; ++i)
        #pragma unroll
        for (int j = 0; j < 4; ++j)
            s[i * 4 + j] = cmul(s01[i], s23[j]);

    float fz0 = 0.f, fz1 = 0.f, fz2 = 0.f, fz3 = 0.f;
    #pragma unroll
    for (int i = 0; i < 16; ++i) {
        float2 acc = make_float2(0.f, 0.f);
        #pragma unroll
        for (int j = 0; j < 16; ++j)
            acc = cadd(acc, cmul(U[i * 16 + j], s[j]));
        float pr = acc.x * acc.x + acc.y * acc.y;
        fz0 += ((i >> 3) & 1) ? -pr : pr;
        fz1 += ((i >> 2) & 1) ? -pr : pr;
        fz2 += ((i >> 1) & 1) ? -pr : pr;
        fz3 += (i & 1) ? -pr : pr;
    }
    float o = head_b[0];
    o = fmaf(fz0, head_w[0], o);
    o = fmaf(fz1, head_w[1], o);
    o = fmaf(fz2, head_w[2], o);
    o = fmaf(fz3, head_w[3], o);
    o = bn_g[0] * (o - bn_m[0]) / sqrtf(bn_v[0] + 1e-5f) + bn_b[0];
    out[b] = o;
}

extern "C" void kernel_launch(void* const* d_in, const int* in_sizes, int n_in,
                              void* d_out, int out_size, void* d_ws, size_t ws_size,
                              hipStream_t stream)
{
    const float* X  = (const float*)d_in[0];
    const float* W1 = (const float*)d_in[1];
    const float* B1 = (const float*)d_in[2];
    const float* W2 = (const float*)d_in[3];
    const float* B2 = (const float*)d_in[4];
    const float* RL = (const float*)d_in[5];
    const float* QP = (const float*)d_in[6];
    const float* HW = (const float*)d_in[7];
    const float* HB = (const float*)d_in[8];
    const float* BG = (const float*)d_in[9];
    const float* BB = (const float*)d_in[10];
    const float* BM = (const float*)d_in[11];
    const float* BV = (const float*)d_in[12];
    float* out = (float*)d_out;

    const size_t H1_BYTES = (size_t)1024 * 8 * 1024 * 4;   // 33.55 MB conv1-pooled maps

    if (ws_size >= H1_BYTES + 4096) {
        float*  h1g = (float*)d_ws;
        float2* U   = (float2*)((char*)d_ws + H1_BYTES);
        conv1_kernel<<<2049, 256, 0, stream>>>(X, W1, B1, h1g, RL, QP, U);
        conv2_head_kernel<<<1024, 256, 0, stream>>>(h1g, W2, B2, U,
                                                    HW, HB, BG, BB, BM, BV, out);
    } else {
        // fallback: Round-1/2 verified fused path (needs only ~66 KB of ws)
        float*  pooled = (float*)d_ws;
        float2* U      = (float2*)((char*)d_ws + 1024 * 16 * 4);
        unitary_lds_kernel<<<1, 256, 0, stream>>>(RL, QP, U);
        fused_cnn_kernel<<<1024, 256, 0, stream>>>(X, W1, B1, W2, B2, pooled);
        quantum_head_kernel<<<4, 256, 0, stream>>>(pooled, U, HW, HB, BG, BB, BM, BV, out);
    }
}

// Round 17
// 69.654 us; speedup vs baseline: 1.7625x; 1.0730x over previous
//
#include <hip/hip_runtime.h>
#include <math.h>

// ---------------- complex helpers ----------------
__device__ __forceinline__ float2 cmul(float2 a, float2 b) {
    return make_float2(a.x * b.x - a.y * b.y, a.x * b.y + a.y * b.x);
}
__device__ __forceinline__ float2 cadd(float2 a, float2 b) {
    return make_float2(a.x + b.x, a.y + b.y);
}

// ================= compile-time: numpy-legacy MT19937 (RandomState(42)) op generation ========
// Algorithm verified bit-exact Rounds 1-16 (absmax 0.0). Gate sequence baked at compile time.
struct CxOps { int ty[57]; int wa[57]; int wb[57]; };

constexpr CxOps cx_gen() {
    CxOps S{};
    unsigned mt[624] = {};
    mt[0] = 42u;
    for (int i = 1; i < 624; ++i)
        mt[i] = 1812433253u * (mt[i - 1] ^ (mt[i - 1] >> 30)) + (unsigned)i;
    int mti = 624;
    auto nextu = [&]() constexpr -> unsigned {
        if (mti >= 624) {
            for (int i = 0; i < 624; ++i) {
                unsigned y = (mt[i] & 0x80000000u) | (mt[(i + 1) % 624] & 0x7fffffffu);
                mt[i] = mt[(i + 397) % 624] ^ (y >> 1) ^ ((y & 1u) ? 2567483615u : 0u);
            }
            mti = 0;
        }
        unsigned y = mt[mti++];
        y ^= y >> 11;
        y ^= (y << 7)  & 2636928640u;
        y ^= (y << 15) & 4022730752u;
        y ^= y >> 18;
        return y;
    };
    for (int k = 0; k < 50; ++k) {
        unsigned g = nextu() & 3u;
        if (g < 3u) {
            unsigned w = nextu() & 3u;
            S.ty[k] = (int)g; S.wa[k] = (int)w; S.wb[k] = 0;
        } else {
            int arr[4] = {0, 1, 2, 3};
            unsigned j3 = nextu() & 3u;
            { int tmp = arr[3]; arr[3] = arr[j3]; arr[j3] = tmp; }
            unsigned j2 = nextu() & 3u;
            while (j2 > 2u) j2 = nextu() & 3u;
            { int tmp = arr[2]; arr[2] = arr[j2]; arr[j2] = tmp; }
            unsigned j1 = nextu() & 1u;
            { int tmp = arr[1]; arr[1] = arr[j1]; arr[j1] = tmp; }
            S.ty[k] = 3; S.wa[k] = arr[0]; S.wb[k] = arr[1];
        }
    }
    S.ty[50] = 0; S.wa[50] = 0; S.wb[50] = 0;   // rx  @0  (qp[0])
    S.ty[51] = 1; S.wa[51] = 1; S.wb[51] = 0;   // ry  @1  (qp[1])
    S.ty[52] = 2; S.wa[52] = 3; S.wb[52] = 0;   // rz  @3  (qp[2])
    S.ty[53] = 3; S.wa[53] = 0; S.wb[53] = 2;   // crx @(0,2) (qp[3])
    S.ty[54] = 4; S.wa[54] = 3; S.wb[54] = 0;   // H   @3
    S.ty[55] = 5; S.wa[55] = 2; S.wb[55] = 0;   // SX  @2
    S.ty[56] = 6; S.wa[56] = 3; S.wb[56] = 0;   // CNOT@(3,0)
    return S;
}
constexpr CxOps C_OPS = cx_gen();

struct CxMeta { int cm[57]; int tm[57]; };
constexpr CxMeta cx_meta_gen() {
    CxMeta M{};
    for (int k = 0; k < 57; ++k) {
        int ty = C_OPS.ty[k];
        if (ty == 3 || ty == 6) { M.cm[k] = 8 >> C_OPS.wa[k]; M.tm[k] = 8 >> C_OPS.wb[k]; }
        else                    { M.cm[k] = 0;               M.tm[k] = 8 >> C_OPS.wa[k]; }
    }
    return M;
}
constexpr CxMeta C_META = cx_meta_gen();

// shared device body: LDS ping-pong unitary compose (Round-8 verified, I-cache-resident loop)
__device__ __forceinline__ void unitary_body(const float* __restrict__ rl,
                                             const float* __restrict__ qp,
                                             float2* __restrict__ Uout,
                                             float2 (&mats)[57][4], float2 (&buf)[2][256])
{
    const int t = threadIdx.x;
    const int r = t >> 4, c = t & 15;

    if (t < 57) {
        const int ty = C_OPS.ty[t];
        const float th = (t < 50) ? rl[t] : ((t < 54) ? qp[t - 50] : 0.f);
        float sh, ch;
        sincosf(0.5f * th, &sh, &ch);
        float2 m00, m01, m10, m11;
        if (ty == 0 || ty == 3) {
            m00 = make_float2(ch, 0.f); m01 = make_float2(0.f, -sh);
            m10 = make_float2(0.f, -sh); m11 = make_float2(ch, 0.f);
        } else if (ty == 1) {
            m00 = make_float2(ch, 0.f); m01 = make_float2(-sh, 0.f);
            m10 = make_float2(sh, 0.f); m11 = make_float2(ch, 0.f);
        } else if (ty == 2) {
            m00 = make_float2(ch, -sh); m01 = make_float2(0.f, 0.f);
            m10 = make_float2(0.f, 0.f); m11 = make_float2(ch, sh);
        } else if (ty == 4) {
            const float r_ = 0.70710678118654752f;
            m00 = make_float2(r_, 0.f); m01 = make_float2(r_, 0.f);
            m10 = make_float2(r_, 0.f); m11 = make_float2(-r_, 0.f);
        } else if (ty == 5) {
            m00 = make_float2(0.5f, 0.5f);  m01 = make_float2(0.5f, -0.5f);
            m10 = make_float2(0.5f, -0.5f); m11 = make_float2(0.5f, 0.5f);
        } else {
            m00 = make_float2(0.f, 0.f); m01 = make_float2(1.f, 0.f);
            m10 = make_float2(1.f, 0.f); m11 = make_float2(0.f, 0.f);
        }
        mats[t][0] = m00; mats[t][1] = m01; mats[t][2] = m10; mats[t][3] = m11;
    }
    buf[0][t] = make_float2((r == c) ? 1.f : 0.f, 0.f);
    __syncthreads();

    int p = 0;
    #pragma unroll 1
    for (int k = 0; k < 57; ++k) {
        const int cm = C_META.cm[k], tm = C_META.tm[k];
        const float2 m00 = mats[k][0], m01 = mats[k][1];
        const float2 m10 = mats[k][2], m11 = mats[k][3];
        const float2 me = buf[p][t];
        const float2 pv = buf[p][(r ^ tm) * 16 + c];
        float2 nv;
        if (r & tm) nv = cadd(cmul(m10, pv), cmul(m11, me));
        else        nv = cadd(cmul(m00, me), cmul(m01, pv));
        if ((r & cm) != cm) nv = me;
        buf[p ^ 1][t] = nv;
        __syncthreads();
        p ^= 1;
    }
    Uout[t] = buf[p][t];
}

__global__ __launch_bounds__(256)
void unitary_lds_kernel(const float* __restrict__ rl, const float* __restrict__ qp,
                        float2* __restrict__ Uout)
{
    __shared__ float2 mats[57][4];
    __shared__ float2 buf[2][256];
    unitary_body(rl, qp, Uout, mats, buf);
}

// ================= Kernel 1: conv1 + relu + maxpool2 (half-split) + unitary tail-block ======
// Round 17: staging vectorized — 544 float4 row loads (aligned; per-row bounds check only)
// + 68 edge zeros, replacing 2244 scalar loads with per-element checks and /66 index math.
// Staged values identical -> bit-identical output. Named .x/.y/.z/.w only (R4 alloca trap).
__global__ __launch_bounds__(256, 4)
void conv1_kernel(const float* __restrict__ X, const float* __restrict__ W1,
                  const float* __restrict__ B1, float* __restrict__ h1g,
                  const float* __restrict__ rl, const float* __restrict__ qp,
                  float2* __restrict__ Uout)
{
    const int bx = blockIdx.x, t = threadIdx.x;
    __shared__ float xin[34 * 66];

    if (bx == 2048) {
        __shared__ float2 mats[57][4];
        __shared__ float2 buf[2][256];
        unitary_body(rl, qp, Uout, mats, buf);
        return;
    }

    const int b = bx >> 1, h = bx & 1;
    const float* xb = X + (size_t)b * 4096;
    const int rbase = 32 * h - 1;
    {
        const float4* x4 = (const float4*)xb;
        for (int idx = t; idx < 544 + 68; idx += 256) {
            if (idx < 544) {                         // 34 rows x 16 float4 = cols 1..64
                const int row = idx >> 4, q = idx & 15;
                const int gy = rbase + row;
                float4 v = make_float4(0.f, 0.f, 0.f, 0.f);
                if (gy >= 0 && gy < 64) v = x4[gy * 16 + q];
                const int base = row * 66 + q * 4 + 1;
                xin[base + 0] = v.x; xin[base + 1] = v.y;
                xin[base + 2] = v.z; xin[base + 3] = v.w;
            } else {                                 // halo cols 0 and 65, 34 rows
                const int e = idx - 544;
                const int row = e >> 1, side = e & 1;
                xin[row * 66 + side * 65] = 0.f;
            }
        }
    }
    __syncthreads();

    #pragma unroll
    for (int j = 0; j < 2; ++j) {
        const int cell = t + 256 * j;
        const int py = cell >> 5, px = cell & 31;
        const int base = (2 * py) * 66 + 2 * px;
        float win[4][4];
        #pragma unroll
        for (int r = 0; r < 4; ++r) {
            float2 p0 = *(const float2*)&xin[base + r * 66];
            float2 p1 = *(const float2*)&xin[base + r * 66 + 2];
            win[r][0] = p0.x; win[r][1] = p0.y; win[r][2] = p1.x; win[r][3] = p1.y;
        }
        const int gcell = (16 * h + py) * 32 + px;
        #pragma unroll
        for (int g = 0; g < 2; ++g) {
            float acc[4][4];
            #pragma unroll
            for (int o = 0; o < 4; ++o) {
                float bb = B1[g * 4 + o];
                acc[o][0] = bb; acc[o][1] = bb; acc[o][2] = bb; acc[o][3] = bb;
            }
            #pragma unroll
            for (int o = 0; o < 4; ++o) {
                const float* wp = W1 + (g * 4 + o) * 9;
                #pragma unroll
                for (int ky = 0; ky < 3; ++ky)
                    #pragma unroll
                    for (int kx = 0; kx < 3; ++kx) {
                        float w = wp[ky * 3 + kx];
                        acc[o][0] = fmaf(win[ky][kx],         w, acc[o][0]);
                        acc[o][1] = fmaf(win[ky][kx + 1],     w, acc[o][1]);
                        acc[o][2] = fmaf(win[ky + 1][kx],     w, acc[o][2]);
                        acc[o][3] = fmaf(win[ky + 1][kx + 1], w, acc[o][3]);
                    }
            }
            #pragma unroll
            for (int o = 0; o < 4; ++o) {
                float m = fmaxf(fmaxf(acc[o][0], acc[o][1]), fmaxf(acc[o][2], acc[o][3]));
                h1g[((size_t)b * 8 + g * 4 + o) * 1024 + gcell] = fmaxf(m, 0.f);
            }
        }
    }
}

// ================= Kernel 2: conv2 + relu + maxpool2 + avg + quantum head (ic-chunked) ======
// Round-16 verified configuration (unroll-2 bracket midpoint): 74.7 us total, no spill.
__global__ __launch_bounds__(256, 4)
void conv2_head_kernel(const float* __restrict__ h1g, const float* __restrict__ W2,
                       const float* __restrict__ B2, const float2* __restrict__ Ug,
                       const float* __restrict__ head_w, const float* __restrict__ head_b,
                       const float* __restrict__ bn_g, const float* __restrict__ bn_b,
                       const float* __restrict__ bn_m, const float* __restrict__ bn_v,
                       float* __restrict__ out)
{
    const int b = blockIdx.x, t = threadIdx.x;
    __shared__ float h1s[4 * 34 * 34];   // halo-padded, 4 input channels per chunk (18.5 KB)
    __shared__ float2 Ul[256];
    __shared__ float red[16 * 4];
    __shared__ float pool16[16];

    Ul[t] = Ug[t];
    for (int i = t; i < 4 * 34 * 34; i += 256) h1s[i] = 0.f;   // halo stays 0 across chunks

    const int py = t >> 4, px = t & 15;
    const int y0 = 2 * py, x0 = 2 * px;
    const int lane = t & 63, wid = t >> 6;

    float acc[16][4];
    #pragma unroll
    for (int o = 0; o < 16; ++o) {
        float bb = B2[o];
        acc[o][0] = bb; acc[o][1] = bb; acc[o][2] = bb; acc[o][3] = bb;
    }

    const float4* src = (const float4*)(h1g + (size_t)b * 8192);

    #pragma unroll 1
    for (int ch = 0; ch < 2; ++ch) {
        __syncthreads();   // chunk-0: after halo zero; chunk-1: prior reads complete
        #pragma unroll
        for (int k = 0; k < 4; ++k) {
            const int i4 = t + k * 256;          // 1024 float4s per chunk
            const float4 v = src[ch * 1024 + i4];
            const int icl = i4 >> 8, c4 = i4 & 255;
            const int y = c4 >> 3, xq = (c4 & 7) << 2;
            const int base = icl * 1156 + (y + 1) * 34 + (xq + 1);
            h1s[base + 0] = v.x; h1s[base + 1] = v.y;
            h1s[base + 2] = v.z; h1s[base + 3] = v.w;
        }
        __syncthreads();

        #pragma unroll 2
        for (int icl = 0; icl < 4; ++icl) {
            const int base = icl * 1156 + y0 * 34 + x0;
            float win[4][4];
            #pragma unroll
            for (int r = 0; r < 4; ++r) {
                float2 p0 = *(const float2*)&h1s[base + r * 34];
                float2 p1 = *(const float2*)&h1s[base + r * 34 + 2];
                win[r][0] = p0.x; win[r][1] = p0.y; win[r][2] = p1.x; win[r][3] = p1.y;
            }
            const float* wpi = W2 + (size_t)(ch * 4 + icl) * 9;
            #pragma unroll
            for (int o = 0; o < 16; ++o) {
                const float* wp = wpi + (size_t)o * 72;
                #pragma unroll
                for (int ky = 0; ky < 3; ++ky)
                    #pragma unroll
                    for (int kx = 0; kx < 3; ++kx) {
                        float w = wp[ky * 3 + kx];
                        acc[o][0] = fmaf(win[ky][kx],         w, acc[o][0]);
                        acc[o][1] = fmaf(win[ky][kx + 1],     w, acc[o][1]);
                        acc[o][2] = fmaf(win[ky + 1][kx],     w, acc[o][2]);
                        acc[o][3] = fmaf(win[ky + 1][kx + 1], w, acc[o][3]);
                    }
            }
        }
    }

    #pragma unroll
    for (int o = 0; o < 16; ++o) {
        float m = fmaxf(fmaxf(acc[o][0], acc[o][1]), fmaxf(acc[o][2], acc[o][3]));
        float v = fmaxf(m, 0.f);
        #pragma unroll
        for (int off = 32; off > 0; off >>= 1)
            v += __shfl_down(v, off, 64);
        if (lane == 0) red[o * 4 + wid] = v;
    }
    __syncthreads();
    if (t < 16)
        pool16[t] = (red[t * 4] + red[t * 4 + 1] + red[t * 4 + 2] + red[t * 4 + 3]) * (1.0f / 256.0f);
    __syncthreads();

    // ---- quantum head: product state from encoder, amplitude row t, <Z>, linear+BN ----
    if (t < 16) {
        float2 v0[4], v1[4];
        #pragma unroll
        for (int w = 0; w < 4; ++w) {
            float a  = pool16[w];
            float bz = pool16[4 + w];
            float gx = pool16[8 + w];
            float dl = pool16[12 + w];
            float sa, ca, sb, cb, sg, cg, sd, cd;
            sincosf(0.5f * a,  &sa, &ca);
            sincosf(0.5f * bz, &sb, &cb);
            sincosf(0.5f * gx, &sg, &cg);
            sincosf(0.5f * dl, &sd, &cd);
            float2 u0 = make_float2(ca * cb, -ca * sb);
            float2 u1 = make_float2(sa * cb,  sa * sb);
            float2 w0 = make_float2(cg * u0.x + sg * u1.y, cg * u0.y - sg * u1.x);
            float2 w1 = make_float2(sg * u0.y + cg * u1.x, -sg * u0.x + cg * u1.y);
            v0[w] = make_float2(cd * w0.x - sd * w1.x, cd * w0.y - sd * w1.y);
            v1[w] = make_float2(sd * w0.x + cd * w1.x, sd * w0.y + cd * w1.y);
        }
        float2 s01[4], s23[4];
        s01[0] = cmul(v0[0], v0[1]); s01[1] = cmul(v0[0], v1[1]);
        s01[2] = cmul(v1[0], v0[1]); s01[3] = cmul(v1[0], v1[1]);
        s23[0] = cmul(v0[2], v0[3]); s23[1] = cmul(v0[2], v1[3]);
        s23[2] = cmul(v1[2], v0[3]); s23[3] = cmul(v1[2], v1[3]);
        float2 acc2 = make_float2(0.f, 0.f);
        #pragma unroll
        for (int i = 0; i < 4; ++i)
            #pragma unroll
            for (int j = 0; j < 4; ++j) {
                float2 sij = cmul(s01[i], s23[j]);
                acc2 = cadd(acc2, cmul(Ul[t * 16 + i * 4 + j], sij));
            }
        float pr = acc2.x * acc2.x + acc2.y * acc2.y;
        float fz0 = 0.f, fz1 = 0.f, fz2 = 0.f, fz3 = 0.f;
        #pragma unroll
        for (int i = 0; i < 16; ++i) {
            float p = __shfl(pr, i, 64);
            fz0 += ((i >> 3) & 1) ? -p : p;
            fz1 += ((i >> 2) & 1) ? -p : p;
            fz2 += ((i >> 1) & 1) ? -p : p;
            fz3 += (i & 1) ? -p : p;
        }
        if (t == 0) {
            float o = head_b[0];
            o = fmaf(fz0, head_w[0], o);
            o = fmaf(fz1, head_w[1], o);
            o = fmaf(fz2, head_w[2], o);
            o = fmaf(fz3, head_w[3], o);
            o = bn_g[0] * (o - bn_m[0]) / sqrtf(bn_v[0] + 1e-5f) + bn_b[0];
            out[b] = o;
        }
    }
}

// ================= Fallback path (Round-1/2 verified, used only if ws too small) =================
__global__ __launch_bounds__(256, 2)
void fused_cnn_kernel(const float* __restrict__ X,
                      const float* __restrict__ W1, const float* __restrict__ B1,
                      const float* __restrict__ W2, const float* __restrict__ B2,
                      float* __restrict__ pooled)
{
    const int b = blockIdx.x;
    const int t = threadIdx.x;
    __shared__ float xin[66 * 66];
    __shared__ float h1[8 * 34 * 34];
    __shared__ float red[16 * 4];

    const float* xb = X + (size_t)b * (64 * 64);
    for (int idx = t; idx < 66 * 66; idx += 256) {
        int y = idx / 66, x = idx - y * 66;
        float v = 0.f;
        if (y >= 1 && y <= 64 && x >= 1 && x <= 64)
            v = xb[(y - 1) * 64 + (x - 1)];
        xin[idx] = v;
    }
    for (int idx = t; idx < 8 * 34 * 34; idx += 256) h1[idx] = 0.f;
    __syncthreads();

    for (int cell = t; cell < 1024; cell += 256) {
        int py = cell >> 5, px = cell & 31;
        int y0 = 2 * py, x0 = 2 * px;
        float win[4][4];
        #pragma unroll
        for (int r = 0; r < 4; ++r)
            #pragma unroll
            for (int c = 0; c < 4; ++c)
                win[r][c] = xin[(y0 + r) * 66 + (x0 + c)];
        #pragma unroll
        for (int oc = 0; oc < 8; ++oc) {
            float bb = B1[oc];
            float a00 = bb, a01 = bb, a10 = bb, a11 = bb;
            #pragma unroll
            for (int ky = 0; ky < 3; ++ky)
                #pragma unroll
                for (int kx = 0; kx < 3; ++kx) {
                    float w = W1[oc * 9 + ky * 3 + kx];
                    a00 = fmaf(win[ky][kx],         w, a00);
                    a01 = fmaf(win[ky][kx + 1],     w, a01);
                    a10 = fmaf(win[ky + 1][kx],     w, a10);
                    a11 = fmaf(win[ky + 1][kx + 1], w, a11);
                }
            float m = fmaxf(fmaxf(a00, a01), fmaxf(a10, a11));
            h1[oc * (34 * 34) + (py + 1) * 34 + (px + 1)] = fmaxf(m, 0.f);
        }
    }
    __syncthreads();

    const int py = t >> 4, px = t & 15;
    const int y0 = 2 * py, x0 = 2 * px;
    const int lane = t & 63, wid = t >> 6;

    for (int g = 0; g < 4; ++g) {
        float acc[4][4];
        #pragma unroll
        for (int o = 0; o < 4; ++o) {
            float bb = B2[g * 4 + o];
            acc[o][0] = bb; acc[o][1] = bb; acc[o][2] = bb; acc[o][3] = bb;
        }
        for (int ic = 0; ic < 8; ++ic) {
            float win[4][4];
            #pragma unroll
            for (int r = 0; r < 4; ++r)
                #pragma unroll
                for (int c = 0; c < 4; ++c)
                    win[r][c] = h1[ic * (34 * 34) + (y0 + r) * 34 + (x0 + c)];
            #pragma unroll
            for (int o = 0; o < 4; ++o) {
                const float* wp = W2 + (size_t)(g * 4 + o) * 72 + ic * 9;
                #pragma unroll
                for (int ky = 0; ky < 3; ++ky)
                    #pragma unroll
                    for (int kx = 0; kx < 3; ++kx) {
                        float w = wp[ky * 3 + kx];
                        acc[o][0] = fmaf(win[ky][kx],         w, acc[o][0]);
                        acc[o][1] = fmaf(win[ky][kx + 1],     w, acc[o][1]);
                        acc[o][2] = fmaf(win[ky + 1][kx],     w, acc[o][2]);
                        acc[o][3] = fmaf(win[ky + 1][kx + 1], w, acc[o][3]);
                    }
            }
        }
        #pragma unroll
        for (int o = 0; o < 4; ++o) {
            float m = fmaxf(fmaxf(acc[o][0], acc[o][1]), fmaxf(acc[o][2], acc[o][3]));
            float v = fmaxf(m, 0.f);
            #pragma unroll
            for (int off = 32; off > 0; off >>= 1)
                v += __shfl_down(v, off, 64);
            if (lane == 0) red[(g * 4 + o) * 4 + wid] = v;
        }
    }
    __syncthreads();
    if (t < 16) {
        float s = red[t * 4] + red[t * 4 + 1] + red[t * 4 + 2] + red[t * 4 + 3];
        pooled[(size_t)b * 16 + t] = s * (1.0f / 256.0f);
    }
}

__global__ __launch_bounds__(256)
void quantum_head_kernel(const float* __restrict__ pooled, const float2* __restrict__ Uin,
                         const float* __restrict__ head_w, const float* __restrict__ head_b,
                         const float* __restrict__ bn_g, const float* __restrict__ bn_b,
                         const float* __restrict__ bn_m, const float* __restrict__ bn_v,
                         float* __restrict__ out)
{
    __shared__ float2 U[256];
    const int t = threadIdx.x;
    U[t] = Uin[t];
    __syncthreads();
    const int b = blockIdx.x * 256 + t;

    float2 v0[4], v1[4];
    #pragma unroll
    for (int w = 0; w < 4; ++w) {
        float a  = pooled[(size_t)b * 16 + w];
        float bz = pooled[(size_t)b * 16 + 4 + w];
        float gx = pooled[(size_t)b * 16 + 8 + w];
        float dl = pooled[(size_t)b * 16 + 12 + w];
        float sa, ca, sb, cb, sg, cg, sd, cd;
        sincosf(0.5f * a,  &sa, &ca);
        sincosf(0.5f * bz, &sb, &cb);
        sincosf(0.5f * gx, &sg, &cg);
        sincosf(0.5f * dl, &sd, &cd);
        float2 u0 = make_float2(ca * cb, -ca * sb);
        float2 u1 = make_float2(sa * cb,  sa * sb);
        float2 w0 = make_float2(cg * u0.x + sg * u1.y, cg * u0.y - sg * u1.x);
        float2 w1 = make_float2(sg * u0.y + cg * u1.x, -sg * u0.x + cg * u1.y);
        v0[w] = make_float2(cd * w0.x - sd * w1.x, cd * w0.y - sd * w1.y);
        v1[w] = make_float2(sd * w0.x + cd * w1.x, sd * w0.y + cd * w1.y);
    }
    float2 s01[4], s23[4], s[16];
    s01[0] = cmul(v0[0], v0[1]); s01[1] = cmul(v0[0], v1[1]);
    s01[2] = cmul(v1[0], v0[1]); s01[3] = cmul(v1[0], v1[1]);
    s23[0] = cmul(v0[2], v0[3]); s23[1] = cmul(v0[2], v1[3]);
    s23[2] = cmul(v1[2], v0[3]); s23[3] = cmul(v1[2], v1[3]);
    #pragma unroll
    for (int i = 0; i < 4; ++i)
        #pragma unroll
        for (int j = 0; j < 4; ++j)
            s[i * 4 + j] = cmul(s01[i], s23[j]);

    float fz0 = 0.f, fz1 = 0.f, fz2 = 0.f, fz3 = 0.f;
    #pragma unroll
    for (int i = 0; i < 16; ++i) {
        float2 acc = make_float2(0.f, 0.f);
        #pragma unroll
        for (int j = 0; j < 16; ++j)
            acc = cadd(acc, cmul(U[i * 16 + j], s[j]));
        float pr = acc.x * acc.x + acc.y * acc.y;
        fz0 += ((i >> 3) & 1) ? -pr : pr;
        fz1 += ((i >> 2) & 1) ? -pr : pr;
        fz2 += ((i >> 1) & 1) ? -pr : pr;
        fz3 += (i & 1) ? -pr : pr;
    }
    float o = head_b[0];
    o = fmaf(fz0, head_w[0], o);
    o = fmaf(fz1, head_w[1], o);
    o = fmaf(fz2, head_w[2], o);
    o = fmaf(fz3, head_w[3], o);
    o = bn_g[0] * (o - bn_m[0]) / sqrtf(bn_v[0] + 1e-5f) + bn_b[0];
    out[b] = o;
}

extern "C" void kernel_launch(void* const* d_in, const int* in_sizes, int n_in,
                              void* d_out, int out_size, void* d_ws, size_t ws_size,
                              hipStream_t stream)
{
    const float* X  = (const float*)d_in[0];
    const float* W1 = (const float*)d_in[1];
    const float* B1 = (const float*)d_in[2];
    const float* W2 = (const float*)d_in[3];
    const float* B2 = (const float*)d_in[4];
    const float* RL = (const float*)d_in[5];
    const float* QP = (const float*)d_in[6];
    const float* HW = (const float*)d_in[7];
    const float* HB = (const float*)d_in[8];
    const float* BG = (const float*)d_in[9];
    const float* BB = (const float*)d_in[10];
    const float* BM = (const float*)d_in[11];
    const float* BV = (const float*)d_in[12];
    float* out = (float*)d_out;

    const size_t H1_BYTES = (size_t)1024 * 8 * 1024 * 4;   // 33.55 MB conv1-pooled maps

    if (ws_size >= H1_BYTES + 4096) {
        float*  h1g = (float*)d_ws;
        float2* U   = (float2*)((char*)d_ws + H1_BYTES);
        conv1_kernel<<<2049, 256, 0, stream>>>(X, W1, B1, h1g, RL, QP, U);
        conv2_head_kernel<<<1024, 256, 0, stream>>>(h1g, W2, B2, U,
                                                    HW, HB, BG, BB, BM, BV, out);
    } else {
        // fallback: Round-1/2 verified fused path (needs only ~66 KB of ws)
        float*  pooled = (float*)d_ws;
        float2* U      = (float2*)((char*)d_ws + 1024 * 16 * 4);
        unitary_lds_kernel<<<1, 256, 0, stream>>>(RL, QP, U);
        fused_cnn_kernel<<<1024, 256, 0, stream>>>(X, W1, B1, W2, B2, pooled);
        quantum_head_kernel<<<4, 256, 0, stream>>>(pooled, U, HW, HB, BG, BB, BM, BV, out);
    }
}